// Round 1
// baseline (1842.265 us; speedup 1.0000x reference)
//
#include <hip/hip_runtime.h>
#include <stdint.h>

// ---------------------------------------------------------------------------
// Types
// ---------------------------------------------------------------------------
typedef __bf16 bf16x8 __attribute__((ext_vector_type(8)));
typedef __bf16 bf16x4 __attribute__((ext_vector_type(4)));
typedef float  f32x4  __attribute__((ext_vector_type(4)));
typedef unsigned int u32;

// async global->LDS, 16B per lane. LDS dest = wave-uniform base + lane*16.
__device__ __forceinline__ void gl_lds16(const void* gptr, void* lptr) {
    __builtin_amdgcn_global_load_lds(
        (const __attribute__((address_space(1))) u32*)gptr,
        (__attribute__((address_space(3))) u32*)lptr,
        16, 0, 0);
}

__device__ __forceinline__ float gelu_exact(float x) {
    return 0.5f * x * (1.0f + erff(x * 0.70710678118654752f));
}

// ---------------------------------------------------------------------------
// Zero the output accumulators (harness poisons d_out with 0xAA each call)
// ---------------------------------------------------------------------------
__global__ void zero_out(float* __restrict__ o, int n) {
    int i = blockIdx.x * 256 + threadIdx.x;
    if (i < n) o[i] = 0.0f;
}

// ---------------------------------------------------------------------------
// fp32 [K][N] -> bf16 transposed [N][K] (LDS tile, coalesced both ways)
// ---------------------------------------------------------------------------
__global__ __launch_bounds__(256)
void transpose_to_bf16(const float* __restrict__ src, __bf16* __restrict__ dst,
                       int K, int Ncols) {
    __shared__ float tile[64][65];
    const int bk = blockIdx.x * 64;
    const int bn = blockIdx.y * 64;
    const int tid = threadIdx.x;
    const int tr = tid >> 4;          // 0..15
    const int tc = (tid & 15) * 4;    // 0..60
#pragma unroll
    for (int p = 0; p < 4; ++p) {
        const int r = tr + p * 16;
        float4 v = *(const float4*)&src[(size_t)(bk + r) * Ncols + bn + tc];
        tile[r][tc] = v.x; tile[r][tc + 1] = v.y;
        tile[r][tc + 2] = v.z; tile[r][tc + 3] = v.w;
    }
    __syncthreads();
#pragma unroll
    for (int p = 0; p < 4; ++p) {
        const int rn = tr + p * 16;
        bf16x4 o;
        o[0] = (__bf16)tile[tc + 0][rn];
        o[1] = (__bf16)tile[tc + 1][rn];
        o[2] = (__bf16)tile[tc + 2][rn];
        o[3] = (__bf16)tile[tc + 3][rn];
        *(bf16x4*)&dst[(size_t)(bn + rn) * K + bk + tc] = o;
    }
}

// fp32 -> bf16 flat (rbf_W), n multiple of 4
__global__ void f32_to_bf16(const float* __restrict__ s, __bf16* __restrict__ d, int n) {
    int idx = blockIdx.x * 256 + threadIdx.x;
    if (idx * 4 < n) {
        float4 v = *(const float4*)(s + idx * 4);
        bf16x4 o;
        o[0] = (__bf16)v.x; o[1] = (__bf16)v.y; o[2] = (__bf16)v.z; o[3] = (__bf16)v.w;
        *(bf16x4*)(d + idx * 4) = o;
    }
}

// ---------------------------------------------------------------------------
// Build feat bf16 [CM][1536] = [ x_i | x_j | rbf(dist_ij) @ rbf_W + rbf_b ]
// Row m (global) = (i*128 + j)*2 + b ; dist is exactly [m].
// Block handles 16 rows; rbf_W (bf16 [50][512]) staged in LDS.
// ---------------------------------------------------------------------------
__global__ __launch_bounds__(256)
void build_feat(const float* __restrict__ x,      // [128][2][512]
                const float* __restrict__ dist,   // [32768]
                const __bf16* __restrict__ rbfW,  // [50][512] bf16
                const float* __restrict__ rbf_b,  // [512]
                __bf16* __restrict__ feat,        // [CM][1536] (chunk-local)
                int m0) {
    __shared__ __align__(16) __bf16 Wl[50 * 512];   // 51200 B
    __shared__ float gl[16][52];

    const int tid = threadIdx.x;
    const int mloc0 = blockIdx.x * 16;
    const int mg0 = m0 + mloc0;

    // stage rbf_W: 25600 bf16 = 6400 uint2
    {
        const uint2* s = (const uint2*)rbfW;
        uint2* d = (uint2*)Wl;
#pragma unroll
        for (int c = 0; c < 25; ++c) d[tid + c * 256] = s[tid + c * 256];
    }
    // gaussian expansion g[r][k]
    const float spacing = 12.0f / 49.0f;
    const float coeff = -0.5f / (spacing * spacing);
    for (int idx = tid; idx < 16 * 50; idx += 256) {
        int r = idx / 50, k = idx - r * 50;
        float d = dist[mg0 + r];
        float t = d - (float)k * spacing;
        gl[r][k] = __expf(coeff * t * t);
    }
    __syncthreads();

    const int r = tid >> 4;            // row within block, 0..15
    const int ebase = (tid & 15) * 8;  // lane-contiguous 16B chunks (no LDS conflicts)

    const int mg = mg0 + r;
    const int i = mg >> 8;
    const int j = (mg >> 1) & 127;
    const int b = mg & 1;

    __bf16* frow = feat + (size_t)(mloc0 + r) * 1536;
    const float* xi = x + ((size_t)i * 2 + b) * 512;
    const float* xj = x + ((size_t)j * 2 + b) * 512;

    // segments 0/1: x_i, x_j
#pragma unroll
    for (int t8 = 0; t8 < 4; ++t8) {
        const int e = ebase + t8 * 128;
        float4 a0 = *(const float4*)(xi + e);
        float4 a1 = *(const float4*)(xi + e + 4);
        bf16x8 v;
        v[0]=(__bf16)a0.x; v[1]=(__bf16)a0.y; v[2]=(__bf16)a0.z; v[3]=(__bf16)a0.w;
        v[4]=(__bf16)a1.x; v[5]=(__bf16)a1.y; v[6]=(__bf16)a1.z; v[7]=(__bf16)a1.w;
        *(bf16x8*)(frow + e) = v;
        float4 b0 = *(const float4*)(xj + e);
        float4 b1 = *(const float4*)(xj + e + 4);
        bf16x8 u;
        u[0]=(__bf16)b0.x; u[1]=(__bf16)b0.y; u[2]=(__bf16)b0.z; u[3]=(__bf16)b0.w;
        u[4]=(__bf16)b1.x; u[5]=(__bf16)b1.y; u[6]=(__bf16)b1.z; u[7]=(__bf16)b1.w;
        *(bf16x8*)(frow + 512 + e) = u;
    }

    // segment 2: rbf = g @ rbf_W + rbf_b
    float acc[4][8];
#pragma unroll
    for (int t8 = 0; t8 < 4; ++t8)
#pragma unroll
        for (int q = 0; q < 8; ++q) acc[t8][q] = rbf_b[ebase + t8 * 128 + q];

    for (int k = 0; k < 50; ++k) {
        const float gk = gl[r][k];
#pragma unroll
        for (int t8 = 0; t8 < 4; ++t8) {
            bf16x8 wv = *(const bf16x8*)(Wl + k * 512 + ebase + t8 * 128);
#pragma unroll
            for (int q = 0; q < 8; ++q) acc[t8][q] += gk * (float)wv[q];
        }
    }
#pragma unroll
    for (int t8 = 0; t8 < 4; ++t8) {
        bf16x8 v;
#pragma unroll
        for (int q = 0; q < 8; ++q) v[q] = (__bf16)acc[t8][q];
        *(bf16x8*)(frow + 1024 + ebase + t8 * 128) = v;
    }
}

// ---------------------------------------------------------------------------
// GEMM: C[M][N] = act( A[M][K] @ Bt[N][K]^T + bias ),  act = GELU (+A residual)
// m97 structure: 128x128 tile, BK=32, 4 waves 2x2, 4x4 acc of 16x16x32 MFMA,
// global_load_lds width 16, bf16x8 ds_read_b128 frags.
// All dims multiples of 128/32 -> no bounds checks.
// ---------------------------------------------------------------------------
template <bool RES>
__global__ __launch_bounds__(256)
void gemm_bias_gelu(const __bf16* __restrict__ A,
                    const __bf16* __restrict__ Bt,
                    const float*  __restrict__ bias,
                    __bf16* __restrict__ C,
                    int M, int N, int K) {
    __shared__ __align__(16) __bf16 As[128 * 32];   // 8 KB
    __shared__ __align__(16) __bf16 Bs[128 * 32];   // 8 KB

    const int tid = threadIdx.x;
    const int bm = blockIdx.x;
    const int bn = blockIdx.y;
    const int w = tid >> 6;
    const int lane = tid & 63;

    // staging: chunk c = {tid, tid+256}; row = c>>2, 16B sub = c&3
    const int r0 = tid >> 2;
    const int s0 = tid & 3;
    const size_t Kb = (size_t)K * 2;
    const char* gA0 = (const char*)A + (size_t)(bm * 128 + r0) * Kb + s0 * 16;
    const char* gA1 = gA0 + 64 * Kb;
    const char* gB0 = (const char*)Bt + (size_t)(bn * 128 + r0) * Kb + s0 * 16;
    const char* gB1 = gB0 + 64 * Kb;
    char* lA0 = (char*)As + w * 1024;   // wave-uniform LDS base; lane*16 appended by HW
    char* lA1 = lA0 + 4096;
    char* lB0 = (char*)Bs + w * 1024;
    char* lB1 = lB0 + 4096;

    // wave tiling: 2x2 waves of 64x64; frags
    const int wm = (w >> 1) & 1;
    const int wn = w & 1;
    const int lm = lane & 15;
    const int ko = (lane >> 4) << 3;
    const __bf16* pA = As + (wm * 64 + lm) * 32 + ko;
    const __bf16* pB = Bs + (wn * 64 + lm) * 32 + ko;

    f32x4 acc[4][4];
    const f32x4 zero = {0.0f, 0.0f, 0.0f, 0.0f};
#pragma unroll
    for (int i = 0; i < 4; ++i)
#pragma unroll
        for (int j = 0; j < 4; ++j) acc[i][j] = zero;

    const int nk = K >> 5;
    for (int kb = 0; kb < nk; ++kb) {
        __syncthreads();
        gl_lds16(gA0, lA0);
        gl_lds16(gA1, lA1);
        gl_lds16(gB0, lB0);
        gl_lds16(gB1, lB1);
        gA0 += 64; gA1 += 64; gB0 += 64; gB1 += 64;
        __syncthreads();   // compiler drains vmcnt(0) before s_barrier

        bf16x8 af[4], bfg[4];
#pragma unroll
        for (int i = 0; i < 4; ++i) {
            af[i]  = *(const bf16x8*)(pA + i * 16 * 32);
            bfg[i] = *(const bf16x8*)(pB + i * 16 * 32);
        }
#pragma unroll
        for (int mi = 0; mi < 4; ++mi)
#pragma unroll
            for (int ni = 0; ni < 4; ++ni)
                acc[mi][ni] = __builtin_amdgcn_mfma_f32_16x16x32_bf16(
                    af[mi], bfg[ni], acc[mi][ni], 0, 0, 0);
    }

    // epilogue: C/D layout col = lane&15, row = (lane>>4)*4 + reg
    const int col0 = bn * 128 + wn * 64 + lm;
    const int row0 = bm * 128 + wm * 64 + ((lane >> 4) << 2);
#pragma unroll
    for (int ni = 0; ni < 4; ++ni) {
        const int gn = col0 + ni * 16;
        const float bv = bias[gn];
#pragma unroll
        for (int mi = 0; mi < 4; ++mi) {
            const int gmb = row0 + mi * 16;
#pragma unroll
            for (int rr = 0; rr < 4; ++rr) {
                const int gm = gmb + rr;
                float xv = acc[mi][ni][rr] + bv;
                float gv = gelu_exact(xv);
                if (RES) gv += (float)A[(size_t)gm * K + gn];  // K==N on residual layers
                C[(size_t)gm * N + gn] = (__bf16)gv;
            }
        }
    }
}

// ---------------------------------------------------------------------------
// Head: per row m, e = <h_e[m], eW>+eb ; f = <h_f[m], fW>+fb
// energy[b] += e/3600 ; forces[b,j,c] += f/60 * vec_hat[m,c]
// One wave per 8 rows; lane covers 16 elements of the 1024-dot.
// ---------------------------------------------------------------------------
__global__ __launch_bounds__(256)
void head_reduce(const __bf16* __restrict__ he, const __bf16* __restrict__ hf,
                 const float* __restrict__ eW, const float* __restrict__ fW,
                 const float* __restrict__ eb, const float* __restrict__ fb,
                 const float* __restrict__ vec_hat,
                 float* __restrict__ out, int m0) {
    const int tid = threadIdx.x;
    const int w = tid >> 6, lane = tid & 63;
    __shared__ float epart[2];
    if (tid < 2) epart[tid] = 0.0f;
    __syncthreads();

    float ew[16], fw[16];
#pragma unroll
    for (int q = 0; q < 16; ++q) {
        ew[q] = eW[lane * 16 + q];
        fw[q] = fW[lane * 16 + q];
    }

    float ea0 = 0.0f, ea1 = 0.0f;
    const int lbase = blockIdx.x * 32 + w * 8;
    for (int rr = 0; rr < 8; ++rr) {
        const int lrow = lbase + rr;
        const int m = m0 + lrow;
        const __bf16* pe = he + (size_t)lrow * 1024 + lane * 16;
        const __bf16* pf = hf + (size_t)lrow * 1024 + lane * 16;
        bf16x8 e0 = *(const bf16x8*)pe, e1 = *(const bf16x8*)(pe + 8);
        bf16x8 f0 = *(const bf16x8*)pf, f1 = *(const bf16x8*)(pf + 8);
        float se = 0.0f, sf = 0.0f;
#pragma unroll
        for (int q = 0; q < 8; ++q) {
            se += (float)e0[q] * ew[q] + (float)e1[q] * ew[8 + q];
            sf += (float)f0[q] * fw[q] + (float)f1[q] * fw[8 + q];
        }
#pragma unroll
        for (int off = 32; off > 0; off >>= 1) {
            se += __shfl_down(se, off);
            sf += __shfl_down(sf, off);
        }
        if (lane == 0) {
            float ev = se + eb[0];
            float fv = (sf + fb[0]) * (1.0f / 60.0f);
            if (m & 1) ea1 += ev; else ea0 += ev;
            const int jj = (m >> 1) & 127;
            const int bb = m & 1;
            float* fo = out + 2 + (bb * 128 + jj) * 3;
            atomicAdd(fo + 0, fv * vec_hat[(size_t)m * 3 + 0]);
            atomicAdd(fo + 1, fv * vec_hat[(size_t)m * 3 + 1]);
            atomicAdd(fo + 2, fv * vec_hat[(size_t)m * 3 + 2]);
        }
    }
    if (lane == 0) {
        atomicAdd(&epart[0], ea0);
        atomicAdd(&epart[1], ea1);
    }
    __syncthreads();
    if (tid < 2) atomicAdd(&out[tid], epart[tid] * (1.0f / 3600.0f));
}

// ---------------------------------------------------------------------------
// Launch
// ---------------------------------------------------------------------------
extern "C" void kernel_launch(void* const* d_in, const int* in_sizes, int n_in,
                              void* d_out, int out_size, void* d_ws, size_t ws_size,
                              hipStream_t stream) {
    const float* x     = (const float*)d_in[0];
    const float* dist  = (const float*)d_in[1];
    const float* vec   = (const float*)d_in[2];
    // d_in[3] = mask (all True in this problem; reference reduces to reshape)
    const float* rbfW  = (const float*)d_in[4];
    const float* rbf_b = (const float*)d_in[5];
    const float* eWin  = (const float*)d_in[6];
    const float* ebin  = (const float*)d_in[7];
    const float* eWh   = (const float*)d_in[8];
    const float* ebh   = (const float*)d_in[9];
    const float* eWout = (const float*)d_in[10];
    const float* ebout = (const float*)d_in[11];
    const float* fWin  = (const float*)d_in[12];
    const float* fbin  = (const float*)d_in[13];
    const float* fWh   = (const float*)d_in[14];
    const float* fbh   = (const float*)d_in[15];
    const float* fWout = (const float*)d_in[16];
    const float* fbout = (const float*)d_in[17];
    float* out = (float*)d_out;

    // workspace carve: bf16 transposed weights (fixed), then chunked activations
    char* p = (char*)d_ws;
    __bf16* eWinT = (__bf16*)p; p += (size_t)1024 * 1536 * 2;
    __bf16* fWinT = (__bf16*)p; p += (size_t)1024 * 1536 * 2;
    __bf16* eWhT[3];
    __bf16* fWhT[3];
    for (int l = 0; l < 3; ++l) { eWhT[l] = (__bf16*)p; p += (size_t)1024 * 1024 * 2; }
    for (int l = 0; l < 3; ++l) { fWhT[l] = (__bf16*)p; p += (size_t)1024 * 1024 * 2; }
    __bf16* rbfWb = (__bf16*)p; p += 51200;
    const size_t fixed = (size_t)(p - (char*)d_ws);

    // chunk M so feat(CM*3072B) + 3*h(CM*2048B) fits ws (h_e1 aliases feat)
    int nchunk = 1;
    while (nchunk < 16 && fixed + (size_t)(32768 / nchunk) * 9216 > ws_size) nchunk <<= 1;
    const int CM = 32768 / nchunk;

    __bf16* feat = (__bf16*)p;
    __bf16* he1  = feat;                       // reuses feat region after layer-0 GEMMs
    __bf16* he0  = feat + (size_t)CM * 1536;
    __bf16* hf0  = he0 + (size_t)CM * 1024;
    __bf16* hf1  = hf0 + (size_t)CM * 1024;

    zero_out<<<dim3(4), dim3(256), 0, stream>>>(out, 770);

    transpose_to_bf16<<<dim3(24, 16), dim3(256), 0, stream>>>(eWin, eWinT, 1536, 1024);
    transpose_to_bf16<<<dim3(24, 16), dim3(256), 0, stream>>>(fWin, fWinT, 1536, 1024);
    for (int l = 0; l < 3; ++l) {
        transpose_to_bf16<<<dim3(16, 16), dim3(256), 0, stream>>>(
            eWh + (size_t)l * 1048576, eWhT[l], 1024, 1024);
        transpose_to_bf16<<<dim3(16, 16), dim3(256), 0, stream>>>(
            fWh + (size_t)l * 1048576, fWhT[l], 1024, 1024);
    }
    f32_to_bf16<<<dim3(25), dim3(256), 0, stream>>>(rbfW, rbfWb, 25600);

    for (int c = 0; c < nchunk; ++c) {
        const int m0 = c * CM;
        build_feat<<<dim3(CM / 16), dim3(256), 0, stream>>>(x, dist, rbfWb, rbf_b, feat, m0);

        const dim3 g(CM / 128, 8), blk(256);
        gemm_bias_gelu<false><<<g, blk, 0, stream>>>(feat, eWinT, ebin, he0, CM, 1024, 1536);
        gemm_bias_gelu<false><<<g, blk, 0, stream>>>(feat, fWinT, fbin, hf0, CM, 1024, 1536);
        // e-branch (he1 overwrites feat — feat already consumed by both layer-0 GEMMs)
        gemm_bias_gelu<true><<<g, blk, 0, stream>>>(he0, eWhT[0], ebh + 0,    he1, CM, 1024, 1024);
        gemm_bias_gelu<true><<<g, blk, 0, stream>>>(he1, eWhT[1], ebh + 1024, he0, CM, 1024, 1024);
        gemm_bias_gelu<true><<<g, blk, 0, stream>>>(he0, eWhT[2], ebh + 2048, he1, CM, 1024, 1024);
        // f-branch
        gemm_bias_gelu<true><<<g, blk, 0, stream>>>(hf0, fWhT[0], fbh + 0,    hf1, CM, 1024, 1024);
        gemm_bias_gelu<true><<<g, blk, 0, stream>>>(hf1, fWhT[1], fbh + 1024, hf0, CM, 1024, 1024);
        gemm_bias_gelu<true><<<g, blk, 0, stream>>>(hf0, fWhT[2], fbh + 2048, hf1, CM, 1024, 1024);

        head_reduce<<<dim3(CM / 32), dim3(256), 0, stream>>>(
            he1, hf1, eWout, fWout, ebout, fbout, vec, out, m0);
    }
}

// Round 2
// 1746.440 us; speedup vs baseline: 1.0549x; 1.0549x over previous
//
#include <hip/hip_runtime.h>
#include <stdint.h>

typedef __bf16 bf16x8 __attribute__((ext_vector_type(8)));
typedef __bf16 bf16x4 __attribute__((ext_vector_type(4)));
typedef float  f32x4  __attribute__((ext_vector_type(4)));
typedef unsigned int u32;

__device__ __forceinline__ void gl_lds16(const void* gptr, void* lptr) {
    __builtin_amdgcn_global_load_lds(
        (const __attribute__((address_space(1))) u32*)gptr,
        (__attribute__((address_space(3))) u32*)lptr,
        16, 0, 0);
}

__device__ __forceinline__ float gelu_exact(float x) {
    return 0.5f * x * (1.0f + erff(x * 0.70710678118654752f));
}

__global__ void zero_out(float* __restrict__ o, int n) {
    int i = blockIdx.x * 256 + threadIdx.x;
    if (i < n) o[i] = 0.0f;
}

// ---------------------------------------------------------------------------
// fp32 [K][N] -> bf16 transposed [N][K]
// ---------------------------------------------------------------------------
__global__ __launch_bounds__(256)
void transpose_to_bf16(const float* __restrict__ src, __bf16* __restrict__ dst,
                       int K, int Ncols) {
    __shared__ float tile[64][65];
    const int bk = blockIdx.x * 64;
    const int bn = blockIdx.y * 64;
    const int tid = threadIdx.x;
    const int tr = tid >> 4;
    const int tc = (tid & 15) * 4;
#pragma unroll
    for (int p = 0; p < 4; ++p) {
        const int r = tr + p * 16;
        float4 v = *(const float4*)&src[(size_t)(bk + r) * Ncols + bn + tc];
        tile[r][tc] = v.x; tile[r][tc + 1] = v.y;
        tile[r][tc + 2] = v.z; tile[r][tc + 3] = v.w;
    }
    __syncthreads();
#pragma unroll
    for (int p = 0; p < 4; ++p) {
        const int rn = tr + p * 16;
        bf16x4 o;
        o[0] = (__bf16)tile[tc + 0][rn];
        o[1] = (__bf16)tile[tc + 1][rn];
        o[2] = (__bf16)tile[tc + 2][rn];
        o[3] = (__bf16)tile[tc + 3][rn];
        *(bf16x4*)&dst[(size_t)(bn + rn) * K + bk + tc] = o;
    }
}

__global__ void f32_to_bf16(const float* __restrict__ s, __bf16* __restrict__ d, int n) {
    int idx = blockIdx.x * 256 + threadIdx.x;
    if (idx * 4 < n) {
        float4 v = *(const float4*)(s + idx * 4);
        bf16x4 o;
        o[0] = (__bf16)v.x; o[1] = (__bf16)v.y; o[2] = (__bf16)v.z; o[3] = (__bf16)v.w;
        *(bf16x4*)(d + idx * 4) = o;
    }
}

// ---------------------------------------------------------------------------
// feat bf16 [CM][1536] = [ x_i | x_j | rbf(dist)@rbf_W + rbf_b ]
// ---------------------------------------------------------------------------
__global__ __launch_bounds__(256)
void build_feat(const float* __restrict__ x, const float* __restrict__ dist,
                const __bf16* __restrict__ rbfW, const float* __restrict__ rbf_b,
                __bf16* __restrict__ feat, int m0) {
    __shared__ __align__(16) __bf16 Wl[50 * 512];
    __shared__ float gl[16][52];

    const int tid = threadIdx.x;
    const int mloc0 = blockIdx.x * 16;
    const int mg0 = m0 + mloc0;

    {
        const uint2* s = (const uint2*)rbfW;
        uint2* d = (uint2*)Wl;
#pragma unroll
        for (int c = 0; c < 25; ++c) d[tid + c * 256] = s[tid + c * 256];
    }
    const float spacing = 12.0f / 49.0f;
    const float coeff = -0.5f / (spacing * spacing);
    for (int idx = tid; idx < 16 * 50; idx += 256) {
        int r = idx / 50, k = idx - r * 50;
        float d = dist[mg0 + r];
        float t = d - (float)k * spacing;
        gl[r][k] = __expf(coeff * t * t);
    }
    __syncthreads();

    const int r = tid >> 4;
    const int ebase = (tid & 15) * 8;

    const int mg = mg0 + r;
    const int i = mg >> 8;
    const int j = (mg >> 1) & 127;
    const int b = mg & 1;

    __bf16* frow = feat + (size_t)(mloc0 + r) * 1536;
    const float* xi = x + ((size_t)i * 2 + b) * 512;
    const float* xj = x + ((size_t)j * 2 + b) * 512;

#pragma unroll
    for (int t8 = 0; t8 < 4; ++t8) {
        const int e = ebase + t8 * 128;
        float4 a0 = *(const float4*)(xi + e);
        float4 a1 = *(const float4*)(xi + e + 4);
        bf16x8 v;
        v[0]=(__bf16)a0.x; v[1]=(__bf16)a0.y; v[2]=(__bf16)a0.z; v[3]=(__bf16)a0.w;
        v[4]=(__bf16)a1.x; v[5]=(__bf16)a1.y; v[6]=(__bf16)a1.z; v[7]=(__bf16)a1.w;
        *(bf16x8*)(frow + e) = v;
        float4 b0 = *(const float4*)(xj + e);
        float4 b1 = *(const float4*)(xj + e + 4);
        bf16x8 u;
        u[0]=(__bf16)b0.x; u[1]=(__bf16)b0.y; u[2]=(__bf16)b0.z; u[3]=(__bf16)b0.w;
        u[4]=(__bf16)b1.x; u[5]=(__bf16)b1.y; u[6]=(__bf16)b1.z; u[7]=(__bf16)b1.w;
        *(bf16x8*)(frow + 512 + e) = u;
    }

    float acc[4][8];
#pragma unroll
    for (int t8 = 0; t8 < 4; ++t8)
#pragma unroll
        for (int q = 0; q < 8; ++q) acc[t8][q] = rbf_b[ebase + t8 * 128 + q];

    for (int k = 0; k < 50; ++k) {
        const float gk = gl[r][k];
#pragma unroll
        for (int t8 = 0; t8 < 4; ++t8) {
            bf16x8 wv = *(const bf16x8*)(Wl + k * 512 + ebase + t8 * 128);
#pragma unroll
            for (int q = 0; q < 8; ++q) acc[t8][q] += gk * (float)wv[q];
        }
    }
#pragma unroll
    for (int t8 = 0; t8 < 4; ++t8) {
        bf16x8 v;
#pragma unroll
        for (int q = 0; q < 8; ++q) v[q] = (__bf16)acc[t8][q];
        *(bf16x8*)(frow + 1024 + ebase + t8 * 128) = v;
    }
}

// ---------------------------------------------------------------------------
// GEMM with double-buffered LDS (single barrier per K-step).
//   CAT : N=2048, cols<1024 -> C0/bias0, else C1/bias1 (layer-0 e|f merged)
//   RES : v = gelu(acc+b) + A[gm][gn]   (hidden layers, K==1024)
//   HEAD: no C write; rowdot += v * wout[gn]; shuffle-reduce; atomicAdd dotArr
// ---------------------------------------------------------------------------
template <bool RES, bool CAT, bool HEAD>
__global__ __launch_bounds__(256)
void gemm_fused(const __bf16* __restrict__ A, const __bf16* __restrict__ Bt,
                const float* __restrict__ bias0, const float* __restrict__ bias1,
                __bf16* __restrict__ C0, __bf16* __restrict__ C1,
                const float* __restrict__ wout, float* __restrict__ dotArr,
                int K) {
    __shared__ __align__(16) __bf16 As[2][128 * 32];   // 2 x 8 KB
    __shared__ __align__(16) __bf16 Bs[2][128 * 32];   // 2 x 8 KB

    const int tid = threadIdx.x;
    const int bm = blockIdx.x;
    const int bn = blockIdx.y;
    const int w = tid >> 6;
    const int lane = tid & 63;

    const int r0 = tid >> 2;
    const int s0 = tid & 3;
    const size_t Kb = (size_t)K * 2;
    const char* gA0 = (const char*)A + (size_t)(bm * 128 + r0) * Kb + s0 * 16;
    const char* gA1 = gA0 + 64 * Kb;
    const char* gB0 = (const char*)Bt + (size_t)(bn * 128 + r0) * Kb + s0 * 16;
    const char* gB1 = gB0 + 64 * Kb;

    char* lA[2] = { (char*)&As[0][0] + w * 1024, (char*)&As[1][0] + w * 1024 };
    char* lB[2] = { (char*)&Bs[0][0] + w * 1024, (char*)&Bs[1][0] + w * 1024 };

    const int wm = (w >> 1) & 1;
    const int wn = w & 1;
    const int lm = lane & 15;
    const int ko = (lane >> 4) << 3;
    const int fo = (wm * 64 + lm) * 32 + ko;   // A frag offset (elements)
    const int go = (wn * 64 + lm) * 32 + ko;   // B frag offset

    f32x4 acc[4][4];
    const f32x4 zero = {0.0f, 0.0f, 0.0f, 0.0f};
#pragma unroll
    for (int i = 0; i < 4; ++i)
#pragma unroll
        for (int j = 0; j < 4; ++j) acc[i][j] = zero;

    auto stage = [&](int buf) {
        gl_lds16(gA0, lA[buf]); gl_lds16(gA1, lA[buf] + 4096);
        gl_lds16(gB0, lB[buf]); gl_lds16(gB1, lB[buf] + 4096);
        gA0 += 64; gA1 += 64; gB0 += 64; gB1 += 64;
    };
    auto compute = [&](int buf) {
        bf16x8 af[4], bfg[4];
        const __bf16* pa = &As[buf][fo];
        const __bf16* pb = &Bs[buf][go];
#pragma unroll
        for (int i = 0; i < 4; ++i) {
            af[i]  = *(const bf16x8*)(pa + i * 512);
            bfg[i] = *(const bf16x8*)(pb + i * 512);
        }
#pragma unroll
        for (int mi = 0; mi < 4; ++mi)
#pragma unroll
            for (int ni = 0; ni < 4; ++ni)
                acc[mi][ni] = __builtin_amdgcn_mfma_f32_16x16x32_bf16(
                    af[mi], bfg[ni], acc[mi][ni], 0, 0, 0);
    };

    const int nk = K >> 5;   // 32 or 48, always even
    stage(0);
    __syncthreads();
    for (int kb = 0; kb < nk; kb += 2) {
        stage(1);                        // loads for kb+1 overlap compute(kb)
        compute(0);
        __syncthreads();                 // vmcnt(0)+lgkm drain after overlap
        if (kb + 2 < nk) stage(0);
        compute(1);
        __syncthreads();
    }

    // epilogue: C/D layout col = lane&15, row = (lane>>4)*4 + reg
    const int col0 = bn * 128 + wn * 64 + lm;
    const int row0 = bm * 128 + wm * 64 + ((lane >> 4) << 2);

    const bool side = CAT && (bn >= 8);
    const float* bp = side ? bias1 : bias0;
    __bf16* Cout = side ? C1 : C0;

    float rowdot[16];
    if (HEAD) {
#pragma unroll
        for (int q = 0; q < 16; ++q) rowdot[q] = 0.0f;
    }

#pragma unroll
    for (int ni = 0; ni < 4; ++ni) {
        const int gn = col0 + ni * 16;
        const int gnl = CAT ? (gn & 1023) : gn;
        const float bv = bp[gnl];
        const float wv = HEAD ? wout[gn] : 0.0f;
#pragma unroll
        for (int mi = 0; mi < 4; ++mi) {
            const int gmb = row0 + mi * 16;
#pragma unroll
            for (int rr = 0; rr < 4; ++rr) {
                const int gm = gmb + rr;
                float v = gelu_exact(acc[mi][ni][rr] + bv);
                if (RES) v += (float)A[(size_t)gm * K + gn];
                if (HEAD) {
                    rowdot[mi * 4 + rr] += v * wv;
                } else {
                    Cout[(size_t)gm * 1024 + gnl] = (__bf16)v;
                }
            }
        }
    }

    if (HEAD) {
#pragma unroll
        for (int s = 1; s < 16; s <<= 1)
#pragma unroll
            for (int q = 0; q < 16; ++q) rowdot[q] += __shfl_xor(rowdot[q], s);
        if (lm == 0) {
#pragma unroll
            for (int q = 0; q < 16; ++q)
                atomicAdd(&dotArr[row0 + (q >> 2) * 16 + (q & 3)], rowdot[q]);
        }
    }
}

// ---------------------------------------------------------------------------
// finalize: per (b,j) block reduce over i; energy atomics, forces direct store
// ---------------------------------------------------------------------------
__global__ __launch_bounds__(128)
void finalize(const float* __restrict__ dot_e, const float* __restrict__ dot_f,
              const float* __restrict__ eb, const float* __restrict__ fb,
              const float* __restrict__ vec, float* __restrict__ out) {
    const int bj = blockIdx.x;          // bb*128 + jj
    const int bb = bj >> 7, jj = bj & 127;
    const int i = threadIdx.x;
    const int m = (i * 128 + jj) * 2 + bb;
    float e = dot_e[m] + eb[0];
    float f = (dot_f[m] + fb[0]) * (1.0f / 60.0f);
    float fx = f * vec[(size_t)m * 3 + 0];
    float fy = f * vec[(size_t)m * 3 + 1];
    float fz = f * vec[(size_t)m * 3 + 2];
#pragma unroll
    for (int off = 32; off > 0; off >>= 1) {
        e  += __shfl_down(e, off);
        fx += __shfl_down(fx, off);
        fy += __shfl_down(fy, off);
        fz += __shfl_down(fz, off);
    }
    __shared__ float red[2][4];
    const int wv = i >> 6, lane = i & 63;
    if (lane == 0) { red[wv][0] = e; red[wv][1] = fx; red[wv][2] = fy; red[wv][3] = fz; }
    __syncthreads();
    if (i == 0) {
        atomicAdd(&out[bb], (red[0][0] + red[1][0]) * (1.0f / 3600.0f));
        float* fo = out + 2 + bj * 3;
        fo[0] = red[0][1] + red[1][1];
        fo[1] = red[0][2] + red[1][2];
        fo[2] = red[0][3] + red[1][3];
    }
}

// ---------------------------------------------------------------------------
extern "C" void kernel_launch(void* const* d_in, const int* in_sizes, int n_in,
                              void* d_out, int out_size, void* d_ws, size_t ws_size,
                              hipStream_t stream) {
    const float* x     = (const float*)d_in[0];
    const float* dist  = (const float*)d_in[1];
    const float* vec   = (const float*)d_in[2];
    const float* rbfW  = (const float*)d_in[4];
    const float* rbf_b = (const float*)d_in[5];
    const float* eWin  = (const float*)d_in[6];
    const float* ebin  = (const float*)d_in[7];
    const float* eWh   = (const float*)d_in[8];
    const float* ebh   = (const float*)d_in[9];
    const float* eWout = (const float*)d_in[10];
    const float* ebout = (const float*)d_in[11];
    const float* fWin  = (const float*)d_in[12];
    const float* fbin  = (const float*)d_in[13];
    const float* fWh   = (const float*)d_in[14];
    const float* fbh   = (const float*)d_in[15];
    const float* fWout = (const float*)d_in[16];
    const float* fbout = (const float*)d_in[17];
    float* out = (float*)d_out;

    // fixed carve: eWinT|fWinT contiguous (CAT weights), WhT x6, rbfW, dots
    char* p = (char*)d_ws;
    __bf16* WinTcat = (__bf16*)p;                 // [2048][1536]
    __bf16* eWinT = WinTcat;          p += (size_t)1024 * 1536 * 2;
    __bf16* fWinT = (__bf16*)p;       p += (size_t)1024 * 1536 * 2;
    __bf16* eWhT[3];
    __bf16* fWhT[3];
    for (int l = 0; l < 3; ++l) { eWhT[l] = (__bf16*)p; p += (size_t)1024 * 1024 * 2; }
    for (int l = 0; l < 3; ++l) { fWhT[l] = (__bf16*)p; p += (size_t)1024 * 1024 * 2; }
    __bf16* rbfWb = (__bf16*)p;       p += 51200;
    float* dot_e = (float*)p;         p += 32768 * 4;
    float* dot_f = (float*)p;         p += 32768 * 4;
    const size_t fixed = (size_t)(p - (char*)d_ws);

    // arena: feat (3072 B/row, later aliased by he1/hf1) + he0 + hf0 (2048 each)
    int nchunk = 1;
    while (nchunk < 16 && fixed + (size_t)(32768 / nchunk) * 7168 > ws_size) nchunk <<= 1;
    const int CM = 32768 / nchunk;

    __bf16* feat = (__bf16*)p;                      // CM*1536 elems
    __bf16* hAlt = feat;                            // he1 / hf1 alias (CM*1024)
    __bf16* he0  = feat + (size_t)CM * 1536;
    __bf16* hf0  = he0 + (size_t)CM * 1024;

    zero_out<<<dim3(4), dim3(256), 0, stream>>>(out, 770);
    zero_out<<<dim3(256), dim3(256), 0, stream>>>(dot_e, 65536);   // dot_e+dot_f contiguous

    transpose_to_bf16<<<dim3(24, 16), dim3(256), 0, stream>>>(eWin, eWinT, 1536, 1024);
    transpose_to_bf16<<<dim3(24, 16), dim3(256), 0, stream>>>(fWin, fWinT, 1536, 1024);
    for (int l = 0; l < 3; ++l) {
        transpose_to_bf16<<<dim3(16, 16), dim3(256), 0, stream>>>(
            eWh + (size_t)l * 1048576, eWhT[l], 1024, 1024);
        transpose_to_bf16<<<dim3(16, 16), dim3(256), 0, stream>>>(
            fWh + (size_t)l * 1048576, fWhT[l], 1024, 1024);
    }
    f32_to_bf16<<<dim3(25), dim3(256), 0, stream>>>(rbfW, rbfWb, 25600);

    for (int c = 0; c < nchunk; ++c) {
        const int m0 = c * CM;
        build_feat<<<dim3(CM / 16), dim3(256), 0, stream>>>(x, dist, rbfWb, rbf_b, feat, m0);

        const dim3 blk(256);
        // layer-0 merged: feat @ [eWin|fWin] -> he0, hf0
        gemm_fused<false, true, false><<<dim3(CM / 128, 16), blk, 0, stream>>>(
            feat, WinTcat, ebin, fbin, he0, hf0, nullptr, nullptr, 1536);
        // e-branch
        gemm_fused<true, false, false><<<dim3(CM / 128, 8), blk, 0, stream>>>(
            he0, eWhT[0], ebh + 0, nullptr, hAlt, nullptr, nullptr, nullptr, 1024);
        gemm_fused<true, false, false><<<dim3(CM / 128, 8), blk, 0, stream>>>(
            hAlt, eWhT[1], ebh + 1024, nullptr, he0, nullptr, nullptr, nullptr, 1024);
        gemm_fused<true, false, true><<<dim3(CM / 128, 8), blk, 0, stream>>>(
            he0, eWhT[2], ebh + 2048, nullptr, nullptr, nullptr, eWout, dot_e + m0, 1024);
        // f-branch (hAlt free after e-layer1 consumed it; he0 free after e-head)
        gemm_fused<true, false, false><<<dim3(CM / 128, 8), blk, 0, stream>>>(
            hf0, fWhT[0], fbh + 0, nullptr, hAlt, nullptr, nullptr, nullptr, 1024);
        gemm_fused<true, false, false><<<dim3(CM / 128, 8), blk, 0, stream>>>(
            hAlt, fWhT[1], fbh + 1024, nullptr, hf0, nullptr, nullptr, nullptr, 1024);
        gemm_fused<true, false, true><<<dim3(CM / 128, 8), blk, 0, stream>>>(
            hf0, fWhT[2], fbh + 2048, nullptr, nullptr, nullptr, fWout, dot_f + m0, 1024);
    }

    finalize<<<dim3(256), dim3(128), 0, stream>>>(dot_e, dot_f, ebout, fbout, vec, out);
}